// Round 14
// baseline (131.782 us; speedup 1.0000x reference)
//
#include <hip/hip_runtime.h>
#include <hip/hip_cooperative_groups.h>

// Problem sizes
#define LN   512      // FFT length
#define FB   257      // rfft bins = L/2+1
#define CB   128      // channels
#define NROW 2048     // B*C rows
#define KF   260      // padded f (65 * 4) for mfma K-loop
#define NP   272      // padded g (17 * 16) — At cols & Zt rows

typedef double double4_t __attribute__((ext_vector_type(4)));

// ---------------------------------------------------------------------------
// Kernel 1 (r13 verbatim): blocks [0,1024): paired real FFT, register
// radix-4 rounds; blocks [1024,1577): At transpose+pad; [1577,1625): xft pad.
// ---------------------------------------------------------------------------
__global__ __launch_bounds__(128)
void k_fftprep(const float* __restrict__ x, const float* __restrict__ A,
               double* __restrict__ xft, double* __restrict__ At_d) {
    const int bx  = blockIdx.x;
    const int tid = threadIdx.x;  // 0..127

    if (bx >= 1024) {
        if (bx < 1577) {                     // At transpose + pad
            int idx = (bx - 1024) * 128 + tid;
            if (idx < KF * NP) {
                int f = idx / NP, g = idx - f * NP;
                At_d[idx] = (f < FB && g < FB) ? (double)A[g * FB + f] : 0.0;
            }
        } else {                             // xft pad rows 257..259
            int idx = (bx - 1577) * 128 + tid;   // 48*128 = 6144 = 3*2048
            xft[(size_t)FB * NROW + idx] = 0.0;
        }
        return;
    }

    __shared__ double2 a[LN];
    __shared__ double2 tw[256];
    const int r0 = bx * 2;

    const double PI = 3.14159265358979323846264338327950288;
    for (int t = tid; t < 256; t += 128) {
        double s, c;
        sincos(-2.0 * PI * (double)t / 512.0, &s, &c);
        tw[t] = make_double2(c, s);
    }

    const float* x0 = x + (size_t)r0 * LN;
    const float* x1 = x0 + LN;
    #pragma unroll
    for (int q = 0; q < 4; ++q) {
        int n = tid + 128 * q;
        int r = (int)(__brev((unsigned)n) >> 23);  // 9-bit reverse
        a[r] = make_double2((double)x0[n], (double)x1[n]);
    }
    __syncthreads();

    #pragma unroll
    for (int s = 1; s <= 7; s += 2) {
        const int h    = 1 << (s - 1);
        const int k    = tid & (h - 1);
        const int grp  = tid >> (s - 1);
        const int base = (grp << (s + 1)) + k;

        double2 a0 = a[base];
        double2 a1 = a[base + h];
        double2 a2 = a[base + 2 * h];
        double2 a3 = a[base + 3 * h];
        double2 w1  = tw[k << (9 - s)];
        double2 w20 = tw[k << (8 - s)];
        double2 w21 = tw[(k + h) << (8 - s)];

        double vr = a1.x * w1.x - a1.y * w1.y;
        double vi = a1.x * w1.y + a1.y * w1.x;
        double2 t0 = make_double2(a0.x + vr, a0.y + vi);
        double2 t1 = make_double2(a0.x - vr, a0.y - vi);
        vr = a3.x * w1.x - a3.y * w1.y;
        vi = a3.x * w1.y + a3.y * w1.x;
        double2 t2 = make_double2(a2.x + vr, a2.y + vi);
        double2 t3 = make_double2(a2.x - vr, a2.y - vi);

        vr = t2.x * w20.x - t2.y * w20.y;
        vi = t2.x * w20.y + t2.y * w20.x;
        a[base]         = make_double2(t0.x + vr, t0.y + vi);
        a[base + 2 * h] = make_double2(t0.x - vr, t0.y - vi);
        vr = t3.x * w21.x - t3.y * w21.y;
        vi = t3.x * w21.y + t3.y * w21.x;
        a[base + h]     = make_double2(t1.x + vr, t1.y + vi);
        a[base + 3 * h] = make_double2(t1.x - vr, t1.y - vi);
        __syncthreads();
    }

    #pragma unroll
    for (int u = 0; u < 2; ++u) {
        int t = tid + 128 * u;
        double2 w  = tw[t];
        double2 uu = a[t];
        double2 v  = a[t + 256];
        double vr = v.x * w.x - v.y * w.y;
        double vi = v.x * w.y + v.y * w.x;
        a[t]       = make_double2(uu.x + vr, uu.y + vi);
        a[t + 256] = make_double2(uu.x - vr, uu.y - vi);
    }
    __syncthreads();

    for (int k = tid; k < FB; k += 128) {
        int m = (LN - k) & (LN - 1);
        double2 zk = a[k];
        double2 zm = a[m];
        double xr = 0.5 * (zk.x + zm.x);
        double xi = 0.5 * (zk.y - zm.y);
        double yr = 0.5 * (zk.y + zm.y);
        double yi = 0.5 * (zm.x - zk.x);
        double m0 = sqrt(xr * xr + xi * xi);
        double m1 = sqrt(yr * yr + yi * yi);
        *(double2*)&xft[(size_t)k * NROW + r0] = make_double2(m0, m1);
    }
}

// ---------------------------------------------------------------------------
// Kernel 2 (cooperative mega-kernel): zmat -> grid.sync -> gram -> grid.sync
// -> mask.  256 blocks x 512 threads (1 block/CU, co-resident).
// Phase bodies are VERBATIM from the verified r13 kernels; only the
// wave->tile index maps changed.
// ---------------------------------------------------------------------------
__global__ __launch_bounds__(512)
void k_zgm(const double* __restrict__ xft, const double* __restrict__ At_d,
           double* __restrict__ Zt, double* __restrict__ G,
           const float* __restrict__ gu, float* __restrict__ out) {
    namespace cg = cooperative_groups;
    cg::grid_group grid = cg::this_grid();

    __shared__ double sn[4][CB];
    __shared__ double wm[4][2];

    const int bx  = blockIdx.x;     // 0..255
    const int tid = threadIdx.x;    // 0..511
    const int w   = tid >> 6;       // 0..7
    const int l   = tid & 63;
    const int q   = l >> 4;         // k-slot 0..3
    const int m   = l & 15;

    // ---- phase 1: zmat.  wave-tiles T in [0,2176): gt=T%17, cht=T/17.
    {
        const int W = bx * 8 + w;   // 0..2047
        for (int T = W; T < 2176; T += 2048) {
            const int gt  = T % 17;
            const int cht = T / 17;
            const int g0  = gt * 16;
            const int ch0 = cht * 16;

            const double* pa = At_d + (size_t)q * NP + g0 + m;
            const double* pb = xft + (size_t)q * NROW + ch0 + m;

            double4_t acc = {0.0, 0.0, 0.0, 0.0};
            double a0 = pa[0],              b0 = pb[0];
            double a1 = pa[(size_t)4 * NP], b1 = pb[(size_t)4 * NROW];
            for (int it = 0; it < 63; ++it) {
                double a2 = pa[(size_t)(it + 2) * 4 * NP];
                double b2 = pb[(size_t)(it + 2) * 4 * NROW];
                acc = __builtin_amdgcn_mfma_f64_16x16x4f64(a0, b0, acc, 0, 0, 0);
                a0 = a1; a1 = a2; b0 = b1; b1 = b2;
            }
            acc = __builtin_amdgcn_mfma_f64_16x16x4f64(a0, b0, acc, 0, 0, 0);
            acc = __builtin_amdgcn_mfma_f64_16x16x4f64(a1, b1, acc, 0, 0, 0);

            const int b   = cht >> 3;
            const int chL = ((cht & 7) << 4) + m;
            double* zp = Zt + ((size_t)b * NP + g0 + q) * CB + chL;
            #pragma unroll
            for (int r = 0; r < 4; ++r) zp[(size_t)(4 * r) * CB] = acc[r];
        }
    }
    grid.sync();

    // ---- phase 2: gram.  tiles W in [0,1024): b=W>>6, it=(W>>3)&7, jt=W&7.
    {
        const int W = bx * 8 + w;
        if (W < 1024) {
            const int b  = W >> 6;
            const int it = (W >> 3) & 7;
            const int jt = W & 7;
            const int i0 = it * 16, j0 = jt * 16;

            const double* zb = Zt + (size_t)b * NP * CB;
            const double* pa = zb + (size_t)q * CB + i0 + m;
            const double* pb = zb + (size_t)q * CB + j0 + m;

            double4_t acc = {0.0, 0.0, 0.0, 0.0};
            double a0 = pa[0],    b0 = pb[0];
            double a1 = pa[512],  b1 = pb[512];
            double a2 = pa[1024], b2 = pb[1024];
            double a3 = pa[1536], b3 = pb[1536];
            for (int t2 = 0; t2 < 61; ++t2) {
                double an = pa[(size_t)(t2 + 4) * 512];
                double bn = pb[(size_t)(t2 + 4) * 512];
                acc = __builtin_amdgcn_mfma_f64_16x16x4f64(a0, b0, acc, 0, 0, 0);
                a0 = a1; a1 = a2; a2 = a3; a3 = an;
                b0 = b1; b1 = b2; b2 = b3; b3 = bn;
            }
            acc = __builtin_amdgcn_mfma_f64_16x16x4f64(a0, b0, acc, 0, 0, 0);
            acc = __builtin_amdgcn_mfma_f64_16x16x4f64(a1, b1, acc, 0, 0, 0);
            acc = __builtin_amdgcn_mfma_f64_16x16x4f64(a2, b2, acc, 0, 0, 0);
            acc = __builtin_amdgcn_mfma_f64_16x16x4f64(a3, b3, acc, 0, 0, 0);

            double* gp = G + ((size_t)(b * CB + i0 + q)) * CB + j0 + m;
            #pragma unroll
            for (int r = 0; r < 4; ++r) gp[(size_t)(4 * r) * CB] = acc[r];
        }
    }
    grid.sync();

    // ---- phase 3: mask.  8 rows per block: 2 reps x 4 slots of 128 thr.
    {
        const int slot = tid >> 7;      // 0..3
        const int j    = tid & 127;
        #pragma unroll
        for (int rep = 0; rep < 2; ++rep) {
            const int bi = bx * 8 + rep * 4 + slot;   // 0..2047
            const int i  = bi & (CB - 1);
            const int b  = bi >> 7;

            double nj = G[((size_t)(b * CB + j)) * CB + j];  // diag = ||Z_j||^2
            double Gv = G[(size_t)bi * CB + j];
            sn[slot][j] = nj;
            __syncthreads();
            double ni = sn[slot][i];
            double dist = ni + nj - 2.0 * Gv;

            double ed = 1.0 / (dist + 3e-8);
            if (j == i) ed = 0.0;            // * (1 - eye)

            double mx = ed;
            #pragma unroll
            for (int off = 32; off >= 1; off >>= 1)
                mx = fmax(mx, __shfl_xor(mx, off, 64));
            if ((j & 63) == 0) wm[slot][j >> 6] = mx;
            __syncthreads();
            double emax = fmax(wm[slot][0], wm[slot][1]);

            double p = ed / (emax + 1e-8);
            if (j == i) p += 1.0;            // + eye
            p *= 0.99;
            double L = log((p + 1e-8) / (1.0 - p + 1e-8));

            float2 u2 = ((const float2*)gu)[(size_t)bi * CB + j];
            double w0 = -log((double)u2.x + 1e-20);
            double w1 = -log((double)u2.y + 1e-20);
            double R = log((w0 + 1e-20) / (w1 + 1e-20));

            // a0 - a1 = 2*logits + g0 - g1 = 2L - R ; tie -> index 0 -> 1
            out[(size_t)bi * CB + j] = (2.0 * L >= R) ? 1.0f : 0.0f;
            __syncthreads();                 // protect sn/wm before next rep
        }
    }
}

// ---------------------------------------------------------------------------
extern "C" void kernel_launch(void* const* d_in, const int* in_sizes, int n_in,
                              void* d_out, int out_size, void* d_ws, size_t ws_size,
                              hipStream_t stream) {
    const float* x  = (const float*)d_in[0];   // (16,128,512)
    const float* A  = (const float*)d_in[1];   // (257,257)
    const float* gu = (const float*)d_in[2];   // (16,128,128,2)
    float* out = (float*)d_out;                // (16,1,128,128)

    char* base = (char*)d_ws;
    const size_t szAt  = (size_t)KF * NP * 8;        //   565,760
    const size_t szXft = (size_t)KF * NROW * 8;      // 4,259,840
    const size_t szZt  = (size_t)16 * NP * CB * 8;   // 4,456,448

    double* At_d = (double*)base;
    double* xft  = (double*)(base + szAt);
    double* Zt   = (double*)(base + szAt + szXft);
    double* G    = (double*)(base + szAt + szXft + szZt);

    hipLaunchKernelGGL(k_fftprep, dim3(1625), dim3(128), 0, stream, x, A, xft, At_d);

    void* args[] = {(void*)&xft, (void*)&At_d, (void*)&Zt, (void*)&G,
                    (void*)&gu, (void*)&out};
    hipLaunchCooperativeKernel((const void*)k_zgm, dim3(256), dim3(512),
                               args, 0, stream);
}

// Round 15
// 52.387 us; speedup vs baseline: 2.5156x; 2.5156x over previous
//
#include <hip/hip_runtime.h>

// Problem sizes
#define LN   512      // FFT length
#define FB   257      // rfft bins = L/2+1
#define CB   128      // channels
#define NROW 2048     // B*C rows
#define KF   260      // padded f (65 * 4) for mfma K-loop
#define NP   272      // padded g (17 * 16) — At cols & Zt rows

// LDS bank-despread swizzle for the FFT array: bijective on [0,512),
// XORs the low 3 bits (which select the bank quad for 16B elements) with
// functions of the upper bits so every access round spreads over all quads.
#define SW(i) ((i) ^ (((i) >> 3) & 7) ^ (((i) >> 6) & 7))

typedef double double4_t __attribute__((ext_vector_type(4)));

// ---------------------------------------------------------------------------
// Kernel 1: blocks [0,1024): paired real FFT — one complex-512 FFT per TWO
// input rows (x_r0 + i*x_r1).  Register radix-4 rounds (r13) + XOR-swizzled
// LDS layout (bank-conflict fix).  Output TRANSPOSED: xft[f][row].
// blocks [1024,1577): At_d[f][g] = A[g][f] zero-padded to 260x272.
// blocks [1577,1625): zero xft pad rows f=257..259.
// ---------------------------------------------------------------------------
__global__ __launch_bounds__(128)
void k_fftprep(const float* __restrict__ x, const float* __restrict__ A,
               double* __restrict__ xft, double* __restrict__ At_d) {
    const int bx  = blockIdx.x;
    const int tid = threadIdx.x;  // 0..127

    if (bx >= 1024) {
        if (bx < 1577) {                     // At transpose + pad
            int idx = (bx - 1024) * 128 + tid;
            if (idx < KF * NP) {
                int f = idx / NP, g = idx - f * NP;
                At_d[idx] = (f < FB && g < FB) ? (double)A[g * FB + f] : 0.0;
            }
        } else {                             // xft pad rows 257..259
            int idx = (bx - 1577) * 128 + tid;   // 48*128 = 6144 = 3*2048
            xft[(size_t)FB * NROW + idx] = 0.0;
        }
        return;
    }

    __shared__ double2 a[LN];
    __shared__ double2 tw[256];
    const int r0 = bx * 2;

    const double PI = 3.14159265358979323846264338327950288;
    for (int t = tid; t < 256; t += 128) {
        double s, c;
        sincos(-2.0 * PI * (double)t / 512.0, &s, &c);
        tw[t] = make_double2(c, s);
    }

    const float* x0 = x + (size_t)r0 * LN;
    const float* x1 = x0 + LN;
    #pragma unroll
    for (int q = 0; q < 4; ++q) {
        int n = tid + 128 * q;
        int r = (int)(__brev((unsigned)n) >> 23);  // 9-bit reverse
        a[SW(r)] = make_double2((double)x0[n], (double)x1[n]);
    }
    __syncthreads();   // covers tw writes and bit-reversed input

    // 4 fused radix-4 rounds: stages (1,2),(3,4),(5,6),(7,8)
    #pragma unroll
    for (int s = 1; s <= 7; s += 2) {
        const int h    = 1 << (s - 1);
        const int k    = tid & (h - 1);
        const int grp  = tid >> (s - 1);
        const int base = (grp << (s + 1)) + k;

        double2 a0 = a[SW(base)];
        double2 a1 = a[SW(base + h)];
        double2 a2 = a[SW(base + 2 * h)];
        double2 a3 = a[SW(base + 3 * h)];
        double2 w1  = tw[k << (9 - s)];
        double2 w20 = tw[k << (8 - s)];
        double2 w21 = tw[(k + h) << (8 - s)];

        // stage s: pairs (a0,a1) and (a2,a3), twiddle w1
        double vr = a1.x * w1.x - a1.y * w1.y;
        double vi = a1.x * w1.y + a1.y * w1.x;
        double2 t0 = make_double2(a0.x + vr, a0.y + vi);
        double2 t1 = make_double2(a0.x - vr, a0.y - vi);
        vr = a3.x * w1.x - a3.y * w1.y;
        vi = a3.x * w1.y + a3.y * w1.x;
        double2 t2 = make_double2(a2.x + vr, a2.y + vi);
        double2 t3 = make_double2(a2.x - vr, a2.y - vi);

        // stage s+1: pairs (t0,t2) w/ w20, (t1,t3) w/ w21
        vr = t2.x * w20.x - t2.y * w20.y;
        vi = t2.x * w20.y + t2.y * w20.x;
        a[SW(base)]         = make_double2(t0.x + vr, t0.y + vi);
        a[SW(base + 2 * h)] = make_double2(t0.x - vr, t0.y - vi);
        vr = t3.x * w21.x - t3.y * w21.y;
        vi = t3.x * w21.y + t3.y * w21.x;
        a[SW(base + h)]     = make_double2(t1.x + vr, t1.y + vi);
        a[SW(base + 3 * h)] = make_double2(t1.x - vr, t1.y - vi);
        __syncthreads();
    }

    // stage 9 (half=256): 2 butterflies/thread, disjoint sets
    #pragma unroll
    for (int u = 0; u < 2; ++u) {
        int t = tid + 128 * u;           // k = t, p0 = t, p1 = t+256
        double2 w  = tw[t];
        double2 uu = a[SW(t)];
        double2 v  = a[SW(t + 256)];
        double vr = v.x * w.x - v.y * w.y;
        double vi = v.x * w.y + v.y * w.x;
        a[SW(t)]       = make_double2(uu.x + vr, uu.y + vi);
        a[SW(t + 256)] = make_double2(uu.x - vr, uu.y - vi);
    }
    __syncthreads();

    // unpack: X_k = (Z_k + conj(Z_{N-k}))/2 ; Y_k = (Z_k - conj(Z_{N-k}))/(2i)
    for (int k = tid; k < FB; k += 128) {
        int m = (LN - k) & (LN - 1);
        double2 zk = a[SW(k)];
        double2 zm = a[SW(m)];
        double xr = 0.5 * (zk.x + zm.x);
        double xi = 0.5 * (zk.y - zm.y);
        double yr = 0.5 * (zk.y + zm.y);
        double yi = 0.5 * (zm.x - zk.x);
        double m0 = sqrt(xr * xr + xi * xi);
        double m1 = sqrt(yr * yr + yi * yi);
        *(double2*)&xft[(size_t)k * NROW + r0] = make_double2(m0, m1);
    }
}

// ---------------------------------------------------------------------------
// Kernel 2: Zt[b][g][ch] = sum_f At_d[f][g] * xft[f][b*128+ch] via
// v_mfma_f64_16x16x4.  (VERIFIED)  D row = q + 4*reg.
// ---------------------------------------------------------------------------
__global__ __launch_bounds__(256)
void k_zmat(const double* __restrict__ xft, const double* __restrict__ At_d,
            double* __restrict__ Zt) {
    const int bx  = blockIdx.x;
    const int tid = threadIdx.x;
    const int w   = tid >> 6;
    const int l   = tid & 63;
    const int q   = l >> 4;       // k-slot 0..3
    const int m   = l & 15;

    const int gt  = bx % 17;
    const int cht = (bx / 17) * 4 + w;   // 0..127
    const int g0  = gt * 16;
    const int ch0 = cht * 16;

    const double* pa = At_d + (size_t)q * NP + g0 + m;
    const double* pb = xft + (size_t)q * NROW + ch0 + m;

    double4_t acc = {0.0, 0.0, 0.0, 0.0};
    double a0 = pa[0],              b0 = pb[0];
    double a1 = pa[(size_t)4 * NP], b1 = pb[(size_t)4 * NROW];
    for (int it = 0; it < 63; ++it) {
        double a2 = pa[(size_t)(it + 2) * 4 * NP];
        double b2 = pb[(size_t)(it + 2) * 4 * NROW];
        acc = __builtin_amdgcn_mfma_f64_16x16x4f64(a0, b0, acc, 0, 0, 0);
        a0 = a1; a1 = a2; b0 = b1; b1 = b2;
    }
    acc = __builtin_amdgcn_mfma_f64_16x16x4f64(a0, b0, acc, 0, 0, 0);
    acc = __builtin_amdgcn_mfma_f64_16x16x4f64(a1, b1, acc, 0, 0, 0);

    const int b   = cht >> 3;
    const int chL = ((cht & 7) << 4) + m;
    double* zp = Zt + ((size_t)b * NP + g0 + q) * CB + chL;
    #pragma unroll
    for (int r = 0; r < 4; ++r) zp[(size_t)(4 * r) * CB] = acc[r];
}

// ---------------------------------------------------------------------------
// Kernel 3: Gram G[b][i][j] = sum_g Zt[b][g][i] * Zt[b][g][j] via
// v_mfma_f64_16x16x4.  (VERIFIED)  D row = q + 4*reg.
// ---------------------------------------------------------------------------
__global__ __launch_bounds__(256)
void k_gram(const double* __restrict__ Zt, double* __restrict__ G) {
    const int bx  = blockIdx.x;
    const int tid = threadIdx.x;
    const int w   = tid >> 6;
    const int l   = tid & 63;
    const int q   = l >> 4;
    const int m   = l & 15;

    const int b  = bx >> 4;
    const int it = (bx >> 1) & 7;
    const int jt = (bx & 1) * 4 + w;
    const int i0 = it * 16, j0 = jt * 16;

    const double* zb = Zt + (size_t)b * NP * CB;
    const double* pa = zb + (size_t)q * CB + i0 + m;
    const double* pb = zb + (size_t)q * CB + j0 + m;

    double4_t acc = {0.0, 0.0, 0.0, 0.0};
    double a0 = pa[0],    b0 = pb[0];
    double a1 = pa[512],  b1 = pb[512];
    double a2 = pa[1024], b2 = pb[1024];
    double a3 = pa[1536], b3 = pb[1536];
    for (int t2 = 0; t2 < 61; ++t2) {
        double an = pa[(size_t)(t2 + 4) * 512];
        double bn = pb[(size_t)(t2 + 4) * 512];
        acc = __builtin_amdgcn_mfma_f64_16x16x4f64(a0, b0, acc, 0, 0, 0);
        a0 = a1; a1 = a2; a2 = a3; a3 = an;
        b0 = b1; b1 = b2; b2 = b3; b3 = bn;
    }
    acc = __builtin_amdgcn_mfma_f64_16x16x4f64(a0, b0, acc, 0, 0, 0);
    acc = __builtin_amdgcn_mfma_f64_16x16x4f64(a1, b1, acc, 0, 0, 0);
    acc = __builtin_amdgcn_mfma_f64_16x16x4f64(a2, b2, acc, 0, 0, 0);
    acc = __builtin_amdgcn_mfma_f64_16x16x4f64(a3, b3, acc, 0, 0, 0);

    double* gp = G + ((size_t)(b * CB + i0 + q)) * CB + j0 + m;
    #pragma unroll
    for (int r = 0; r < 4; ++r) gp[(size_t)(4 * r) * CB] = acc[r];
}

// ---------------------------------------------------------------------------
// Kernel 4: dist = n_i + n_j - 2G (norms from G diagonal), rowmax,
// ratio-log logits, gumbel compare -> binary mask.  (VERIFIED, verbatim)
// ---------------------------------------------------------------------------
__global__ __launch_bounds__(128)
void k_mask2(const double* __restrict__ G,
             const float* __restrict__ gu, float* __restrict__ out) {
    __shared__ double sn[CB];
    __shared__ double wmax[2];
    const int bi = blockIdx.x;       // b*128 + i
    const int i  = bi & (CB - 1);
    const int b  = bi >> 7;
    const int j  = threadIdx.x;      // 0..127

    double nj = G[((size_t)(b * CB + j)) * CB + j];   // diagonal = ||Z_j||^2
    double Gv = G[(size_t)bi * CB + j];
    sn[j] = nj;
    __syncthreads();
    double ni = sn[i];
    double dist = ni + nj - 2.0 * Gv;

    double ed = 1.0 / (dist + 3e-8);
    if (j == i) ed = 0.0;            // * (1 - eye)

    double m = ed;
    #pragma unroll
    for (int off = 32; off >= 1; off >>= 1)
        m = fmax(m, __shfl_xor(m, off, 64));
    if ((j & 63) == 0) wmax[j >> 6] = m;
    __syncthreads();
    double emax = fmax(wmax[0], wmax[1]);

    double p = ed / (emax + 1e-8);
    if (j == i) p += 1.0;            // + eye
    p *= 0.99;
    double L = log((p + 1e-8) / (1.0 - p + 1e-8));

    float2 u2 = ((const float2*)gu)[(size_t)bi * CB + j];
    double w0 = -log((double)u2.x + 1e-20);
    double w1 = -log((double)u2.y + 1e-20);
    double R = log((w0 + 1e-20) / (w1 + 1e-20));

    // a0 - a1 = 2*logits + g0 - g1 = 2L - R ; tie -> index 0 -> 1
    out[(size_t)bi * CB + j] = (2.0 * L >= R) ? 1.0f : 0.0f;
}

// ---------------------------------------------------------------------------
extern "C" void kernel_launch(void* const* d_in, const int* in_sizes, int n_in,
                              void* d_out, int out_size, void* d_ws, size_t ws_size,
                              hipStream_t stream) {
    const float* x  = (const float*)d_in[0];   // (16,128,512)
    const float* A  = (const float*)d_in[1];   // (257,257)
    const float* gu = (const float*)d_in[2];   // (16,128,128,2)
    float* out = (float*)d_out;                // (16,1,128,128)

    char* base = (char*)d_ws;
    const size_t szAt  = (size_t)KF * NP * 8;        //   565,760
    const size_t szXft = (size_t)KF * NROW * 8;      // 4,259,840
    const size_t szZt  = (size_t)16 * NP * CB * 8;   // 4,456,448

    double* At_d = (double*)base;
    double* xft  = (double*)(base + szAt);
    double* Zt   = (double*)(base + szAt + szXft);
    double* G    = (double*)(base + szAt + szXft + szZt);

    hipLaunchKernelGGL(k_fftprep, dim3(1625), dim3(128), 0, stream, x, A, xft, At_d);
    hipLaunchKernelGGL(k_zmat,    dim3(544),  dim3(256), 0, stream, xft, At_d, Zt);
    hipLaunchKernelGGL(k_gram,    dim3(256),  dim3(256), 0, stream, Zt, G);
    hipLaunchKernelGGL(k_mask2,   dim3(2048), dim3(128), 0, stream, G, gu, out);
}